// Round 2
// baseline (1616.801 us; speedup 1.0000x reference)
//
#include <hip/hip_runtime.h>
#include <math.h>

// NormVoxels: trilinear gather + sigmoid-weighted scatter-add update.
// R2: counting-sort point indices by spatial key (t,x,y-hi) so consecutive
// threads touch adjacent voxel lines -> L1/L2 reuse + sequential-ish HBM.
// d_in: [0]=t(int32,N) [1]=pos(f32,N*3) [2]=lr(f32,1) [3]=sigma(f32,N)
//       [4]=target_norm(f32,N*3) [5]=voxel_array(f32,8*128^3*3)
// d_out: value(f32,N*3) ++ new_voxel(f32,8*128^3*3)

#define GRES 128
#define NBINS 65536   // key = t(3) | x(7) | y>>1(6)
constexpr float RMIN_F = -1.5f;
constexpr float STEP_F = 3.0f / 128.0f;  // exact in fp32

__device__ __forceinline__ int cell_key(int t, float px, float py) {
    int mx = (int)floorf(px / STEP_F);
    int my = (int)floorf(py / STEP_F);
    int x0 = min(max(mx, 0), GRES - 1);
    int y0 = min(max(my, 0), GRES - 1);
    return (t << 13) | (x0 << 6) | (y0 >> 1);
}

__global__ __launch_bounds__(256) void hist_kernel(
    const int* __restrict__ t, const float* __restrict__ pos,
    unsigned* __restrict__ hist, int N)
{
    int i = blockIdx.x * blockDim.x + threadIdx.x;
    if (i >= N) return;
    float px = pos[3 * i + 0] - RMIN_F;
    float py = pos[3 * i + 1] - RMIN_F;
    atomicAdd(&hist[cell_key(t[i], px, py)], 1u);
}

// Single-workgroup scan: 1024 threads x 64 bins each.
__global__ __launch_bounds__(1024) void scan_kernel(
    const unsigned* __restrict__ hist, unsigned* __restrict__ cursor)
{
    __shared__ unsigned sums[1024];
    const int tid = threadIdx.x;
    const int base = tid * 64;
    unsigned s = 0;
    for (int k = 0; k < 64; ++k) s += hist[base + k];
    sums[tid] = s;
    __syncthreads();
    // Hillis-Steele inclusive scan over 1024 partials
    for (int off = 1; off < 1024; off <<= 1) {
        unsigned v = (tid >= off) ? sums[tid - off] : 0u;
        __syncthreads();
        sums[tid] += v;
        __syncthreads();
    }
    unsigned running = sums[tid] - s;  // exclusive prefix of this thread's chunk
    for (int k = 0; k < 64; ++k) {
        cursor[base + k] = running;
        running += hist[base + k];
    }
}

__global__ __launch_bounds__(256) void scatter_kernel(
    const int* __restrict__ t, const float* __restrict__ pos,
    unsigned* __restrict__ cursor, unsigned* __restrict__ order, int N)
{
    int i = blockIdx.x * blockDim.x + threadIdx.x;
    if (i >= N) return;
    float px = pos[3 * i + 0] - RMIN_F;
    float py = pos[3 * i + 1] - RMIN_F;
    unsigned slot = atomicAdd(&cursor[cell_key(t[i], px, py)], 1u);
    order[slot] = (unsigned)i;
}

__global__ __launch_bounds__(256) void normvoxels_update(
    const unsigned* __restrict__ order,
    const int*   __restrict__ t,
    const float* __restrict__ pos,
    const float* __restrict__ lr_p,
    const float* __restrict__ sigma,
    const float* __restrict__ target,
    const float* __restrict__ voxel_in,
    float*       __restrict__ out_value,
    float*       __restrict__ out_voxel,
    int N)
{
    int ii = blockIdx.x * blockDim.x + threadIdx.x;
    if (ii >= N) return;
    const int i = (int)order[ii];

    const float lr = lr_p[0];

    const float px = pos[3 * i + 0] - RMIN_F;
    const float py = pos[3 * i + 1] - RMIN_F;
    const float pz = pos[3 * i + 2] - RMIN_F;

    const int mx = (int)floorf(px / STEP_F);
    const int my = (int)floorf(py / STEP_F);
    const int mz = (int)floorf(pz / STEP_F);

    const float u = fmodf(px, STEP_F) / STEP_F;
    const float v = fmodf(py, STEP_F) / STEP_F;
    const float w = fmodf(pz, STEP_F) / STEP_F;

    const int x0 = min(max(mx,     0), GRES - 1);
    const int x1 = min(max(mx + 1, 0), GRES - 1);
    const int y0 = min(max(my,     0), GRES - 1);
    const int y1 = min(max(my + 1, 0), GRES - 1);
    const int z0 = min(max(mz,     0), GRES - 1);
    const int z1 = min(max(mz + 1, 0), GRES - 1);

    float c[8];
    c[0] = (1.f - u) * (1.f - v) * (1.f - w);
    c[1] =        u  * (1.f - v) * (1.f - w);
    c[2] = (1.f - u) *        v  * (1.f - w);
    c[3] =        u  *        v  * (1.f - w);
    c[4] = (1.f - u) * (1.f - v) *        w;
    c[5] =        u  * (1.f - v) *        w;
    c[6] = (1.f - u) *        v  *        w;
    c[7] =        u  *        v  *        w;

    const float sw = 1.0f - expf(-sigma[i]);
    const float lrsw = lr * sw;

    const float tx = target[3 * i + 0];
    const float ty = target[3 * i + 1];
    const float tz = target[3 * i + 2];

    const size_t tbase = (size_t)t[i] * GRES * GRES * GRES * 3;

    float vx = 0.f, vy = 0.f, vz = 0.f;

    #pragma unroll
    for (int k = 0; k < 8; ++k) {
        const int xi = (k & 1) ? x1 : x0;
        const int yi = (k & 2) ? y1 : y0;
        const int zi = (k & 4) ? z1 : z0;
        const size_t base = tbase + (((size_t)xi * GRES + yi) * GRES + zi) * 3;

        const float a0 = voxel_in[base + 0];
        const float a1 = voxel_in[base + 1];
        const float a2 = voxel_in[base + 2];

        vx += c[k] * a0;
        vy += c[k] * a1;
        vz += c[k] * a2;

        const float lam = 1.0f / (1.0f + expf(-lrsw * c[k]));

        atomicAdd(out_voxel + base + 0, lam * (tx - a0));
        atomicAdd(out_voxel + base + 1, lam * (ty - a1));
        atomicAdd(out_voxel + base + 2, lam * (tz - a2));
    }

    out_value[3 * i + 0] = vx;
    out_value[3 * i + 1] = vy;
    out_value[3 * i + 2] = vz;
}

extern "C" void kernel_launch(void* const* d_in, const int* in_sizes, int n_in,
                              void* d_out, int out_size, void* d_ws, size_t ws_size,
                              hipStream_t stream) {
    const int*   t      = (const int*)  d_in[0];
    const float* pos    = (const float*)d_in[1];
    const float* lr     = (const float*)d_in[2];
    const float* sigma  = (const float*)d_in[3];
    const float* target = (const float*)d_in[4];
    const float* voxel  = (const float*)d_in[5];

    const int N    = in_sizes[0];           // 1048576 points
    const int nvox = in_sizes[5];           // 8*128^3*3 floats

    float* out_value = (float*)d_out;
    float* out_voxel = out_value + (size_t)3 * N;

    // ws layout: hist[NBINS] | cursor[NBINS] | order[N]  (~4.5 MB)
    unsigned* hist   = (unsigned*)d_ws;
    unsigned* cursor = hist + NBINS;
    unsigned* order  = cursor + NBINS;

    const int block = 256;
    const int grid  = (N + block - 1) / block;

    hipMemsetAsync(hist, 0, NBINS * sizeof(unsigned), stream);
    hist_kernel<<<grid, block, 0, stream>>>(t, pos, hist, N);
    scan_kernel<<<1, 1024, 0, stream>>>(hist, cursor);
    scatter_kernel<<<grid, block, 0, stream>>>(t, pos, cursor, order, N);

    // new_voxel starts as a copy of voxel_array; atomics then add diffs.
    hipMemcpyAsync(out_voxel, voxel, (size_t)nvox * sizeof(float),
                   hipMemcpyDeviceToDevice, stream);

    normvoxels_update<<<grid, block, 0, stream>>>(
        order, t, pos, lr, sigma, target, voxel, out_value, out_voxel, N);
}

// Round 3
// 706.331 us; speedup vs baseline: 2.2890x; 2.2890x over previous
//
#include <hip/hip_runtime.h>
#include <math.h>

// NormVoxels R3: voxel-owned bricks, zero global atomics.
//  1) counting-sort points by cell-column key (t,x,y) with packed 32B payload
//  2) one workgroup per 4x4x128-voxel brick: stage voxel_in (5x5x128 halo) in
//     LDS, accumulate lam*(target - v) via LDS atomics from the 25 halo cell
//     columns, write out = staged + accum coalesced. Brick owning the point's
//     cell writes its trilinear value (corners all inside staged halo).
// d_in: [0]=t(i32,N) [1]=pos(f32,N*3) [2]=lr(f32,1) [3]=sigma(f32,N)
//       [4]=target_norm(f32,N*3) [5]=voxel_array(f32,8*128^3*3)
// d_out: value(f32,N*3) ++ new_voxel(f32,8*128^3*3)

#define GRES 128
#define NBINS (8 * 128 * 128)          // key = t(3)|x(7)|y(7)
constexpr float RMIN_F = -1.5f;
constexpr float STEP_F = 3.0f / 128.0f; // exact in fp32

__global__ __launch_bounds__(256) void hist_kernel(
    const int* __restrict__ t, const float* __restrict__ pos,
    unsigned* __restrict__ hist, int N)
{
    int i = blockIdx.x * blockDim.x + threadIdx.x;
    if (i >= N) return;
    float px = pos[3 * i + 0] - RMIN_F;
    float py = pos[3 * i + 1] - RMIN_F;
    int cx = min((int)floorf(px / STEP_F), GRES - 1);
    int cy = min((int)floorf(py / STEP_F), GRES - 1);
    atomicAdd(&hist[(t[i] << 14) | (cx << 7) | cy], 1u);
}

// Single-workgroup scan: 1024 threads x 128 bins each = 131072.
__global__ __launch_bounds__(1024) void scan_kernel(
    const unsigned* __restrict__ hist,
    unsigned* __restrict__ cursor, unsigned* __restrict__ binstart)
{
    __shared__ unsigned sums[1024];
    const int tid = threadIdx.x;
    const int base = tid * 128;
    unsigned s = 0;
    for (int k = 0; k < 128; ++k) s += hist[base + k];
    sums[tid] = s;
    __syncthreads();
    for (int off = 1; off < 1024; off <<= 1) {
        unsigned v = (tid >= off) ? sums[tid - off] : 0u;
        __syncthreads();
        sums[tid] += v;
        __syncthreads();
    }
    unsigned run = sums[tid] - s;  // exclusive prefix of this chunk
    for (int k = 0; k < 128; ++k) {
        unsigned c = hist[base + k];
        cursor[base + k]   = run;
        binstart[base + k] = run;
        run += c;
    }
}

__global__ __launch_bounds__(256) void scatter_kernel(
    const int* __restrict__ t, const float* __restrict__ pos,
    const float* __restrict__ lr_p, const float* __restrict__ sigma,
    const float* __restrict__ target,
    unsigned* __restrict__ cursor, float4* __restrict__ sorted, int N)
{
    int i = blockIdx.x * blockDim.x + threadIdx.x;
    if (i >= N) return;
    float px = pos[3 * i + 0] - RMIN_F;
    float py = pos[3 * i + 1] - RMIN_F;
    float pz = pos[3 * i + 2] - RMIN_F;
    int cx = min((int)floorf(px / STEP_F), GRES - 1);
    int cy = min((int)floorf(py / STEP_F), GRES - 1);
    unsigned slot = atomicAdd(&cursor[(t[i] << 14) | (cx << 7) | cy], 1u);
    float lrsw = lr_p[0] * (1.0f - expf(-sigma[i]));
    sorted[(size_t)slot * 2 + 0] = make_float4(px, py, pz, lrsw);
    sorted[(size_t)slot * 2 + 1] = make_float4(target[3 * i + 0], target[3 * i + 1],
                                               target[3 * i + 2], __int_as_float(i));
}

__global__ __launch_bounds__(256) void brick_kernel(
    const unsigned* __restrict__ hist,
    const unsigned* __restrict__ binstart,
    const float4*   __restrict__ sorted,
    const float*    __restrict__ voxel_in,
    float*          __restrict__ out_value,
    float*          __restrict__ out_voxel)
{
    __shared__ __align__(16) float s_vox[5 * 5 * 128 * 3];   // 38400 B
    __shared__ __align__(16) float s_acc[4 * 4 * 128 * 3];   // 24576 B
    __shared__ unsigned s_bs[25];
    __shared__ unsigned s_pref[26];

    // XCD-slab swizzle: each XCD gets one contiguous t-slab (L2 halo reuse).
    const int vb = ((blockIdx.x & 7) << 10) | (blockIdx.x >> 3);
    const int t  = vb >> 10;
    const int bx = (vb >> 5) & 31;
    const int by = vb & 31;
    const int x0 = bx << 2, y0 = by << 2;
    const int tid = threadIdx.x;

    const size_t tbase = (size_t)t * (GRES * GRES * GRES * 3);

    // Stage voxel_in for [x0..x0+4] x [y0..y0+4] x z (clamped at edge).
    float4* s_vox4 = (float4*)s_vox;
    for (int q = tid; q < 25 * 96; q += 256) {
        int row = q / 96, r = q - row * 96;
        int sx = row / 5, sy = row - sx * 5;
        int gx = min(x0 + sx, GRES - 1), gy = min(y0 + sy, GRES - 1);
        const float4* src = (const float4*)(voxel_in + tbase +
                                            (size_t)gx * 49152 + (size_t)gy * 384);
        s_vox4[row * 96 + r] = src[r];
    }
    float4* s_acc4 = (float4*)s_acc;
    for (int q = tid; q < 16 * 96; q += 256) s_acc4[q] = make_float4(0.f, 0.f, 0.f, 0.f);

    if (tid < 25) {
        int dxb = tid / 5 - 1, dyb = tid % 5 - 1;
        int cx = x0 + dxb, cy = y0 + dyb;
        unsigned cnt = 0, st = 0;
        if (cx >= 0 && cx < GRES && cy >= 0 && cy < GRES) {
            int key = (t << 14) | (cx << 7) | cy;
            cnt = hist[key];
            st  = binstart[key];
        }
        s_bs[tid] = st;
        s_pref[tid + 1] = cnt;
    }
    __syncthreads();
    if (tid == 0) {
        unsigned run = 0;
        s_pref[0] = 0;
        for (int b = 0; b < 25; ++b) {
            unsigned c = s_pref[b + 1];
            s_pref[b + 1] = run + c;
            run += c;
        }
    }
    __syncthreads();
    const int P = (int)s_pref[25];

    for (int j = tid; j < P; j += 256) {
        int b = 0;
        while (s_pref[b + 1] <= (unsigned)j) ++b;
        int g = (int)(s_bs[b] + ((unsigned)j - s_pref[b]));
        float4 pa = sorted[(size_t)g * 2 + 0];
        float4 pb = sorted[(size_t)g * 2 + 1];
        const float px = pa.x, py = pa.y, pz = pa.z, lrsw = pa.w;
        const float tx = pb.x, ty = pb.y, tz = pb.z;
        const int   idx = __float_as_int(pb.w);

        const int mx = (int)floorf(px / STEP_F);
        const int my = (int)floorf(py / STEP_F);
        const int mz = (int)floorf(pz / STEP_F);
        const float u = fmodf(px, STEP_F) / STEP_F;
        const float v = fmodf(py, STEP_F) / STEP_F;
        const float w = fmodf(pz, STEP_F) / STEP_F;

        const int xs0 = min(mx, GRES - 1),     xs1 = min(mx + 1, GRES - 1);
        const int ys0 = min(my, GRES - 1),     ys1 = min(my + 1, GRES - 1);
        const int zs0 = min(mz, GRES - 1),     zs1 = min(mz + 1, GRES - 1);

        float c[8];
        c[0] = (1.f - u) * (1.f - v) * (1.f - w);
        c[1] =        u  * (1.f - v) * (1.f - w);
        c[2] = (1.f - u) *        v  * (1.f - w);
        c[3] =        u  *        v  * (1.f - w);
        c[4] = (1.f - u) * (1.f - v) *        w;
        c[5] =        u  * (1.f - v) *        w;
        c[6] = (1.f - u) *        v  *        w;
        c[7] =        u  *        v  *        w;

        const int dx = min(mx, GRES - 1) - x0;
        const int dy = min(my, GRES - 1) - y0;
        const bool owner = (dx >= 0 && dx < 4 && dy >= 0 && dy < 4);

        float vx = 0.f, vy = 0.f, vz = 0.f;

        #pragma unroll
        for (int k = 0; k < 8; ++k) {
            const int xi = (k & 1) ? xs1 : xs0;
            const int yi = (k & 2) ? ys1 : ys0;
            const int zi = (k & 4) ? zs1 : zs0;
            const int sxi = xi - x0, syi = yi - y0;
            const bool inStage = (sxi >= 0 && syi >= 0);  // upper bound holds by construction
            float a0 = 0.f, a1 = 0.f, a2 = 0.f;
            if (inStage) {
                const int sv = ((sxi * 5 + syi) * 128 + zi) * 3;
                a0 = s_vox[sv + 0];
                a1 = s_vox[sv + 1];
                a2 = s_vox[sv + 2];
            }
            if (owner) {
                vx += c[k] * a0;
                vy += c[k] * a1;
                vz += c[k] * a2;
            }
            if (sxi >= 0 && sxi < 4 && syi >= 0 && syi < 4) {
                const float lam = 1.0f / (1.0f + expf(-lrsw * c[k]));
                const int sa = ((sxi * 4 + syi) * 128 + zi) * 3;
                atomicAdd(&s_acc[sa + 0], lam * (tx - a0));
                atomicAdd(&s_acc[sa + 1], lam * (ty - a1));
                atomicAdd(&s_acc[sa + 2], lam * (tz - a2));
            }
        }
        if (owner) {
            out_value[3 * idx + 0] = vx;
            out_value[3 * idx + 1] = vy;
            out_value[3 * idx + 2] = vz;
        }
    }
    __syncthreads();

    // Coalesced write-out: out = staged original + accumulated diff.
    for (int q = tid; q < 16 * 96; q += 256) {
        int row = q / 96, r = q - row * 96;
        int ox = row >> 2, oy = row & 3;
        float4 a = s_vox4[(ox * 5 + oy) * 96 + r];
        float4 d = s_acc4[q];
        float4 o = make_float4(a.x + d.x, a.y + d.y, a.z + d.z, a.w + d.w);
        *((float4*)(out_voxel + tbase + (size_t)(x0 + ox) * 49152 +
                    (size_t)(y0 + oy) * 384) + r) = o;
    }
}

extern "C" void kernel_launch(void* const* d_in, const int* in_sizes, int n_in,
                              void* d_out, int out_size, void* d_ws, size_t ws_size,
                              hipStream_t stream) {
    const int*   t      = (const int*)  d_in[0];
    const float* pos    = (const float*)d_in[1];
    const float* lr     = (const float*)d_in[2];
    const float* sigma  = (const float*)d_in[3];
    const float* target = (const float*)d_in[4];
    const float* voxel  = (const float*)d_in[5];

    const int N = in_sizes[0];              // 1048576 points

    float* out_value = (float*)d_out;
    float* out_voxel = out_value + (size_t)3 * N;

    // ws: sorted payload (16B-aligned, first) | hist | binstart | cursor
    float4*   sorted   = (float4*)d_ws;                       // 2*N float4 = 32 MB
    unsigned* hist     = (unsigned*)(sorted + (size_t)2 * N); // 0.5 MB
    unsigned* binstart = hist + NBINS;                        // 0.5 MB
    unsigned* cursor   = binstart + NBINS;                    // 0.5 MB

    const int block = 256;
    const int grid  = (N + block - 1) / block;

    hipMemsetAsync(hist, 0, NBINS * sizeof(unsigned), stream);
    hist_kernel<<<grid, block, 0, stream>>>(t, pos, hist, N);
    scan_kernel<<<1, 1024, 0, stream>>>(hist, cursor, binstart);
    scatter_kernel<<<grid, block, 0, stream>>>(t, pos, lr, sigma, target,
                                               cursor, sorted, N);
    brick_kernel<<<8192, 256, 0, stream>>>(hist, binstart, sorted, voxel,
                                           out_value, out_voxel);
}

// Round 4
// 566.233 us; speedup vs baseline: 2.8554x; 1.2474x over previous
//
#include <hip/hip_runtime.h>
#include <hip/hip_fp16.h>
#include <math.h>

// NormVoxels R4: voxel-owned bricks, zero global atomics, slim LDS.
//  1) key+hist kernel (caches keys)
//  2) 3-kernel parallel counting-sort scan over 131072 bins
//  3) scatter: 16B compressed payload (u11/v11/w10 fracs, idx20|mz7,
//     fp16 target + lrsw) written to sorted order
//  4) brick kernel: one WG per 4x4x128 brick; ONLY s_acc (24.6KB) in LDS;
//     corner gathers straight from global (L1/L2-resident halo);
//     writeback out = voxel_in (coalesced re-read, L2-hot) + s_acc.
// d_in: [0]=t(i32,N) [1]=pos(f32,N*3) [2]=lr(f32,1) [3]=sigma(f32,N)
//       [4]=target_norm(f32,N*3) [5]=voxel_array(f32,8*128^3*3)
// d_out: value(f32,N*3) ++ new_voxel(f32,8*128^3*3)

#define GRES 128
#define NBINS (8 * 128 * 128)      // key = t(3)|x(7)|y(7)
#define SCAN_BLOCKS 512            // 256 bins per block
constexpr float RMIN_F = -1.5f;
constexpr float STEP_F = 3.0f / 128.0f;  // exact in fp32

__global__ __launch_bounds__(256) void key_hist_kernel(
    const int* __restrict__ t, const float* __restrict__ pos,
    unsigned* __restrict__ keys, unsigned* __restrict__ hist, int N)
{
    int i = blockIdx.x * blockDim.x + threadIdx.x;
    if (i >= N) return;
    float px = pos[3 * i + 0] - RMIN_F;
    float py = pos[3 * i + 1] - RMIN_F;
    int cx = min((int)floorf(px / STEP_F), GRES - 1);
    int cy = min((int)floorf(py / STEP_F), GRES - 1);
    unsigned key = ((unsigned)t[i] << 14) | ((unsigned)cx << 7) | (unsigned)cy;
    keys[i] = key;
    atomicAdd(&hist[key], 1u);
}

// scanA: per-block local exclusive scan of 256 bins + block total.
__global__ __launch_bounds__(256) void scanA_kernel(
    const unsigned* __restrict__ hist, unsigned* __restrict__ binstart,
    unsigned* __restrict__ partial)
{
    __shared__ unsigned sh[256];
    const int tid = threadIdx.x;
    const int gid = blockIdx.x * 256 + tid;
    unsigned x = hist[gid];
    sh[tid] = x;
    __syncthreads();
    for (int off = 1; off < 256; off <<= 1) {
        unsigned v = (tid >= off) ? sh[tid - off] : 0u;
        __syncthreads();
        sh[tid] += v;
        __syncthreads();
    }
    binstart[gid] = sh[tid] - x;               // local exclusive
    if (tid == 255) partial[blockIdx.x] = sh[255];
}

// scanB: exclusive scan of 512 block totals.
__global__ __launch_bounds__(512) void scanB_kernel(
    const unsigned* __restrict__ partial, unsigned* __restrict__ offs)
{
    __shared__ unsigned sh[512];
    const int tid = threadIdx.x;
    unsigned x = partial[tid];
    sh[tid] = x;
    __syncthreads();
    for (int off = 1; off < 512; off <<= 1) {
        unsigned v = (tid >= off) ? sh[tid - off] : 0u;
        __syncthreads();
        sh[tid] += v;
        __syncthreads();
    }
    offs[tid] = sh[tid] - x;
}

// scanC: apply block offsets; produce cursor copy + sentinel.
__global__ __launch_bounds__(256) void scanC_kernel(
    unsigned* __restrict__ binstart, const unsigned* __restrict__ offs,
    unsigned* __restrict__ cursor, int N)
{
    const int gid = blockIdx.x * 256 + threadIdx.x;
    unsigned v = binstart[gid] + offs[blockIdx.x];
    binstart[gid] = v;
    cursor[gid]   = v;
    if (gid == 0) binstart[NBINS] = (unsigned)N;
}

__global__ __launch_bounds__(256) void scatter_kernel(
    const float* __restrict__ pos, const float* __restrict__ lr_p,
    const float* __restrict__ sigma, const float* __restrict__ target,
    const unsigned* __restrict__ keys,
    unsigned* __restrict__ cursor, uint4* __restrict__ sorted, int N)
{
    int i = blockIdx.x * blockDim.x + threadIdx.x;
    if (i >= N) return;
    unsigned key  = keys[i];
    unsigned slot = atomicAdd(&cursor[key], 1u);

    float px = pos[3 * i + 0] - RMIN_F;
    float py = pos[3 * i + 1] - RMIN_F;
    float pz = pos[3 * i + 2] - RMIN_F;
    float u = fmodf(px, STEP_F) / STEP_F;
    float v = fmodf(py, STEP_F) / STEP_F;
    float w = fmodf(pz, STEP_F) / STEP_F;
    int   mz = min((int)floorf(pz / STEP_F), GRES - 1);

    unsigned qu = (unsigned)(u * 2047.0f + 0.5f);   // u<1 -> <=2047
    unsigned qv = (unsigned)(v * 2047.0f + 0.5f);
    unsigned qw = (unsigned)(w * 1023.0f + 0.5f);

    float lrsw = lr_p[0] * (1.0f - expf(-sigma[i]));

    unsigned hx = (unsigned)__half_as_ushort(__float2half(target[3 * i + 0]));
    unsigned hy = (unsigned)__half_as_ushort(__float2half(target[3 * i + 1]));
    unsigned hz = (unsigned)__half_as_ushort(__float2half(target[3 * i + 2]));
    unsigned hl = (unsigned)__half_as_ushort(__float2half(lrsw));

    uint4 p;
    p.x = (qu << 21) | (qv << 10) | qw;
    p.y = ((unsigned)i << 7) | (unsigned)mz;        // idx:20 | mz:7
    p.z = hx | (hy << 16);
    p.w = hz | (hl << 16);
    sorted[slot] = p;
}

__global__ __launch_bounds__(256) void brick_kernel(
    const unsigned* __restrict__ binstart,
    const uint4*    __restrict__ sorted,
    const float*    __restrict__ voxel_in,
    float*          __restrict__ out_value,
    float*          __restrict__ out_voxel)
{
    __shared__ __align__(16) float s_acc[4 * 4 * 128 * 3];   // 24576 B
    __shared__ unsigned s_start[25];
    __shared__ unsigned s_pref[26];

    // XCD-slab swizzle: each XCD gets one contiguous t-slab (L2 halo reuse).
    const int vb = ((blockIdx.x & 7) << 10) | (blockIdx.x >> 3);
    const int t  = vb >> 10;
    const int bx = (vb >> 5) & 31;
    const int by = vb & 31;
    const int x0 = bx << 2, y0 = by << 2;
    const int tid = threadIdx.x;
    const size_t tbase = (size_t)t * (GRES * GRES * GRES * 3);

    float4* s_acc4 = (float4*)s_acc;
    for (int q = tid; q < 16 * 96; q += 256) s_acc4[q] = make_float4(0.f, 0.f, 0.f, 0.f);

    if (tid < 25) {
        int dxb = tid / 5 - 1, dyb = tid % 5 - 1;
        int cx = x0 + dxb, cy = y0 + dyb;
        unsigned st = 0, cnt = 0;
        if (cx >= 0 && cx < GRES && cy >= 0 && cy < GRES) {
            unsigned key = ((unsigned)t << 14) | ((unsigned)cx << 7) | (unsigned)cy;
            st  = binstart[key];
            cnt = binstart[key + 1] - st;
        }
        s_start[tid] = st;
        s_pref[tid + 1] = cnt;
    }
    __syncthreads();
    if (tid == 0) {
        unsigned run = 0;
        s_pref[0] = 0;
        for (int b = 0; b < 25; ++b) {
            unsigned c = s_pref[b + 1];
            s_pref[b + 1] = run + c;
            run += c;
        }
    }
    __syncthreads();
    const int P = (int)s_pref[25];

    for (int j = tid; j < P; j += 256) {
        int b = 0;
        while (s_pref[b + 1] <= (unsigned)j) ++b;
        const int dxb = b / 5 - 1, dyb = b % 5 - 1;
        const int cx = x0 + dxb, cy = y0 + dyb;
        const unsigned g = s_start[b] + ((unsigned)j - s_pref[b]);

        const uint4 p = sorted[g];
        const float u = (float)(p.x >> 21)          * (1.0f / 2047.0f);
        const float v = (float)((p.x >> 10) & 2047u) * (1.0f / 2047.0f);
        const float w = (float)(p.x & 1023u)         * (1.0f / 1023.0f);
        const int  mz  = (int)(p.y & 127u);
        const int  idx = (int)(p.y >> 7);
        const float tx = __half2float(__ushort_as_half((unsigned short)(p.z & 0xffffu)));
        const float ty = __half2float(__ushort_as_half((unsigned short)(p.z >> 16)));
        const float tz = __half2float(__ushort_as_half((unsigned short)(p.w & 0xffffu)));
        const float lrsw = __half2float(__ushort_as_half((unsigned short)(p.w >> 16)));

        const int xs1 = min(cx + 1, GRES - 1);
        const int ys1 = min(cy + 1, GRES - 1);
        const int zs1 = min(mz + 1, GRES - 1);

        float c[8];
        c[0] = (1.f - u) * (1.f - v) * (1.f - w);
        c[1] =        u  * (1.f - v) * (1.f - w);
        c[2] = (1.f - u) *        v  * (1.f - w);
        c[3] =        u  *        v  * (1.f - w);
        c[4] = (1.f - u) * (1.f - v) *        w;
        c[5] =        u  * (1.f - v) *        w;
        c[6] = (1.f - u) *        v  *        w;
        c[7] =        u  *        v  *        w;

        const bool owner = (dxb >= 0) && (dyb >= 0);
        float vx = 0.f, vy = 0.f, vz = 0.f;

        #pragma unroll
        for (int k = 0; k < 8; ++k) {
            const int xi = (k & 1) ? xs1 : cx;
            const int yi = (k & 2) ? ys1 : cy;
            const int zi = (k & 4) ? zs1 : mz;
            const int sxi = xi - x0, syi = yi - y0;
            const bool inAcc = (sxi >= 0) && (sxi < 4) && (syi >= 0) && (syi < 4);
            if (owner || inAcc) {
                const float* vp = voxel_in + tbase + (((size_t)xi * GRES + yi) * GRES + zi) * 3;
                const float a0 = vp[0];
                const float a1 = vp[1];
                const float a2 = vp[2];
                if (owner) {
                    vx += c[k] * a0;
                    vy += c[k] * a1;
                    vz += c[k] * a2;
                }
                if (inAcc) {
                    const float lam = 1.0f / (1.0f + expf(-lrsw * c[k]));
                    const int sa = ((sxi * 4 + syi) * 128 + zi) * 3;
                    atomicAdd(&s_acc[sa + 0], lam * (tx - a0));
                    atomicAdd(&s_acc[sa + 1], lam * (ty - a1));
                    atomicAdd(&s_acc[sa + 2], lam * (tz - a2));
                }
            }
        }
        if (owner) {
            out_value[3 * idx + 0] = vx;
            out_value[3 * idx + 1] = vy;
            out_value[3 * idx + 2] = vz;
        }
    }
    __syncthreads();

    // Coalesced write-out: out = voxel_in (L2-hot re-read) + accumulated diff.
    for (int q = tid; q < 16 * 96; q += 256) {
        int row = q / 96, r = q - row * 96;
        int ox = row >> 2, oy = row & 3;
        const size_t coff = tbase + (size_t)(x0 + ox) * 49152 + (size_t)(y0 + oy) * 384;
        float4 a = *((const float4*)(voxel_in + coff) + r);
        float4 d = s_acc4[q];
        *((float4*)(out_voxel + coff) + r) =
            make_float4(a.x + d.x, a.y + d.y, a.z + d.z, a.w + d.w);
    }
}

extern "C" void kernel_launch(void* const* d_in, const int* in_sizes, int n_in,
                              void* d_out, int out_size, void* d_ws, size_t ws_size,
                              hipStream_t stream) {
    const int*   t      = (const int*)  d_in[0];
    const float* pos    = (const float*)d_in[1];
    const float* lr     = (const float*)d_in[2];
    const float* sigma  = (const float*)d_in[3];
    const float* target = (const float*)d_in[4];
    const float* voxel  = (const float*)d_in[5];

    const int N = in_sizes[0];              // 1048576 points

    float* out_value = (float*)d_out;
    float* out_voxel = out_value + (size_t)3 * N;

    // ws: sorted(16B*N=16MB) | keys(4MB) | hist | binstart(+1) | cursor | partial | offs
    uint4*    sorted   = (uint4*)d_ws;
    unsigned* keys     = (unsigned*)(sorted + (size_t)N);
    unsigned* hist     = keys + N;
    unsigned* binstart = hist + NBINS;
    unsigned* cursor   = binstart + (NBINS + 1);
    unsigned* partial  = cursor + NBINS;
    unsigned* offs     = partial + SCAN_BLOCKS;

    const int block = 256;
    const int grid  = (N + block - 1) / block;

    hipMemsetAsync(hist, 0, NBINS * sizeof(unsigned), stream);
    key_hist_kernel<<<grid, block, 0, stream>>>(t, pos, keys, hist, N);
    scanA_kernel<<<SCAN_BLOCKS, 256, 0, stream>>>(hist, binstart, partial);
    scanB_kernel<<<1, 512, 0, stream>>>(partial, offs);
    scanC_kernel<<<SCAN_BLOCKS, 256, 0, stream>>>(binstart, offs, cursor, N);
    scatter_kernel<<<grid, block, 0, stream>>>(pos, lr, sigma, target, keys,
                                               cursor, sorted, N);
    brick_kernel<<<8192, 256, 0, stream>>>(binstart, sorted, voxel,
                                           out_value, out_voxel);
}

// Round 5
// 520.797 us; speedup vs baseline: 3.1045x; 1.0872x over previous
//
#include <hip/hip_runtime.h>
#include <hip/hip_fp16.h>
#include <math.h>

// NormVoxels R5: voxel-owned bricks, zero global atomics in scatter.
//  1) key_hist: atomicAdd return = within-bin rank, packed into keys[i]
//  2) 3-kernel parallel scan over 131072 bins
//  3) scatter: slot = binstart[key] + rank (NO atomics), 16B payload
//  4) brick kernel: one WG per 4x4x128 brick; s_acc (24.6KB) LDS only;
//     all 8 corner gathers issued unconditionally (MLP), then predicated
//     value-accum + LDS atomic scatter; coalesced writeback.
// d_in: [0]=t(i32,N) [1]=pos(f32,N*3) [2]=lr(f32,1) [3]=sigma(f32,N)
//       [4]=target_norm(f32,N*3) [5]=voxel_array(f32,8*128^3*3)
// d_out: value(f32,N*3) ++ new_voxel(f32,8*128^3*3)

#define GRES 128
#define NBINS (8 * 128 * 128)      // key = t(3)|x(7)|y(7)  (17 bits)
#define SCAN_BLOCKS 512            // 256 bins per block
constexpr float RMIN_F = -1.5f;
constexpr float STEP_F = 3.0f / 128.0f;  // exact in fp32

__global__ __launch_bounds__(256) void key_hist_kernel(
    const int* __restrict__ t, const float* __restrict__ pos,
    unsigned* __restrict__ keys, unsigned* __restrict__ hist, int N)
{
    int i = blockIdx.x * blockDim.x + threadIdx.x;
    if (i >= N) return;
    float px = pos[3 * i + 0] - RMIN_F;
    float py = pos[3 * i + 1] - RMIN_F;
    int cx = min((int)floorf(px / STEP_F), GRES - 1);
    int cy = min((int)floorf(py / STEP_F), GRES - 1);
    unsigned key  = ((unsigned)t[i] << 14) | ((unsigned)cx << 7) | (unsigned)cy;
    unsigned rank = atomicAdd(&hist[key], 1u);       // free within-bin rank
    keys[i] = (key << 15) | rank;                    // 17b key | 15b rank
}

// scanA: per-block local exclusive scan of 256 bins + block total.
__global__ __launch_bounds__(256) void scanA_kernel(
    const unsigned* __restrict__ hist, unsigned* __restrict__ binstart,
    unsigned* __restrict__ partial)
{
    __shared__ unsigned sh[256];
    const int tid = threadIdx.x;
    const int gid = blockIdx.x * 256 + tid;
    unsigned x = hist[gid];
    sh[tid] = x;
    __syncthreads();
    for (int off = 1; off < 256; off <<= 1) {
        unsigned v = (tid >= off) ? sh[tid - off] : 0u;
        __syncthreads();
        sh[tid] += v;
        __syncthreads();
    }
    binstart[gid] = sh[tid] - x;               // local exclusive
    if (tid == 255) partial[blockIdx.x] = sh[255];
}

// scanB: exclusive scan of 512 block totals.
__global__ __launch_bounds__(512) void scanB_kernel(
    const unsigned* __restrict__ partial, unsigned* __restrict__ offs)
{
    __shared__ unsigned sh[512];
    const int tid = threadIdx.x;
    unsigned x = partial[tid];
    sh[tid] = x;
    __syncthreads();
    for (int off = 1; off < 512; off <<= 1) {
        unsigned v = (tid >= off) ? sh[tid - off] : 0u;
        __syncthreads();
        sh[tid] += v;
        __syncthreads();
    }
    offs[tid] = sh[tid] - x;
}

// scanC: apply block offsets + sentinel.
__global__ __launch_bounds__(256) void scanC_kernel(
    unsigned* __restrict__ binstart, const unsigned* __restrict__ offs, int N)
{
    const int gid = blockIdx.x * 256 + threadIdx.x;
    binstart[gid] += offs[blockIdx.x];
    if (gid == 0) binstart[NBINS] = (unsigned)N;
}

__global__ __launch_bounds__(256) void scatter_kernel(
    const float* __restrict__ pos, const float* __restrict__ lr_p,
    const float* __restrict__ sigma, const float* __restrict__ target,
    const unsigned* __restrict__ keys, const unsigned* __restrict__ binstart,
    uint4* __restrict__ sorted, int N)
{
    int i = blockIdx.x * blockDim.x + threadIdx.x;
    if (i >= N) return;
    unsigned kr   = keys[i];
    unsigned key  = kr >> 15;
    unsigned rank = kr & 0x7fffu;
    unsigned slot = binstart[key] + rank;            // no atomics

    float px = pos[3 * i + 0] - RMIN_F;
    float py = pos[3 * i + 1] - RMIN_F;
    float pz = pos[3 * i + 2] - RMIN_F;
    float u = fmodf(px, STEP_F) / STEP_F;
    float v = fmodf(py, STEP_F) / STEP_F;
    float w = fmodf(pz, STEP_F) / STEP_F;
    int   mz = min((int)floorf(pz / STEP_F), GRES - 1);

    unsigned qu = (unsigned)(u * 2047.0f + 0.5f);
    unsigned qv = (unsigned)(v * 2047.0f + 0.5f);
    unsigned qw = (unsigned)(w * 1023.0f + 0.5f);

    float lrsw = lr_p[0] * (1.0f - expf(-sigma[i]));

    unsigned hx = (unsigned)__half_as_ushort(__float2half(target[3 * i + 0]));
    unsigned hy = (unsigned)__half_as_ushort(__float2half(target[3 * i + 1]));
    unsigned hz = (unsigned)__half_as_ushort(__float2half(target[3 * i + 2]));
    unsigned hl = (unsigned)__half_as_ushort(__float2half(lrsw));

    uint4 p;
    p.x = (qu << 21) | (qv << 10) | qw;
    p.y = ((unsigned)i << 7) | (unsigned)mz;        // idx:20 | mz:7
    p.z = hx | (hy << 16);
    p.w = hz | (hl << 16);
    sorted[slot] = p;
}

__global__ __launch_bounds__(256) void brick_kernel(
    const unsigned* __restrict__ binstart,
    const uint4*    __restrict__ sorted,
    const float*    __restrict__ voxel_in,
    float*          __restrict__ out_value,
    float*          __restrict__ out_voxel)
{
    __shared__ __align__(16) float s_acc[4 * 4 * 128 * 3];   // 24576 B
    __shared__ unsigned s_start[25];
    __shared__ unsigned s_pref[26];

    // XCD-slab swizzle: each XCD gets one contiguous t-slab (L2 halo reuse).
    const int vb = ((blockIdx.x & 7) << 10) | (blockIdx.x >> 3);
    const int t  = vb >> 10;
    const int bx = (vb >> 5) & 31;
    const int by = vb & 31;
    const int x0 = bx << 2, y0 = by << 2;
    const int tid = threadIdx.x;
    const size_t tbase = (size_t)t * (GRES * GRES * GRES * 3);

    float4* s_acc4 = (float4*)s_acc;
    for (int q = tid; q < 16 * 96; q += 256) s_acc4[q] = make_float4(0.f, 0.f, 0.f, 0.f);

    if (tid < 25) {
        int dxb = tid / 5 - 1, dyb = tid % 5 - 1;
        int cx = x0 + dxb, cy = y0 + dyb;
        unsigned st = 0, cnt = 0;
        if (cx >= 0 && cx < GRES && cy >= 0 && cy < GRES) {
            unsigned key = ((unsigned)t << 14) | ((unsigned)cx << 7) | (unsigned)cy;
            st  = binstart[key];
            cnt = binstart[key + 1] - st;
        }
        s_start[tid] = st;
        s_pref[tid + 1] = cnt;
    }
    __syncthreads();
    if (tid == 0) {
        unsigned run = 0;
        s_pref[0] = 0;
        for (int b = 0; b < 25; ++b) {
            unsigned c = s_pref[b + 1];
            s_pref[b + 1] = run + c;
            run += c;
        }
    }
    __syncthreads();
    const int P = (int)s_pref[25];

    for (int j = tid; j < P; j += 256) {
        int b = 0;
        while (s_pref[b + 1] <= (unsigned)j) ++b;
        const int dxb = b / 5 - 1, dyb = b % 5 - 1;
        const int cx = x0 + dxb, cy = y0 + dyb;
        const unsigned g = s_start[b] + ((unsigned)j - s_pref[b]);

        const uint4 p = sorted[g];
        const float u = (float)(p.x >> 21)           * (1.0f / 2047.0f);
        const float v = (float)((p.x >> 10) & 2047u) * (1.0f / 2047.0f);
        const float w = (float)(p.x & 1023u)         * (1.0f / 1023.0f);
        const int  mz  = (int)(p.y & 127u);
        const int  idx = (int)(p.y >> 7);
        const float tx = __half2float(__ushort_as_half((unsigned short)(p.z & 0xffffu)));
        const float ty = __half2float(__ushort_as_half((unsigned short)(p.z >> 16)));
        const float tz = __half2float(__ushort_as_half((unsigned short)(p.w & 0xffffu)));
        const float lrsw = __half2float(__ushort_as_half((unsigned short)(p.w >> 16)));

        const int xs1 = min(cx + 1, GRES - 1);
        const int ys1 = min(cy + 1, GRES - 1);
        const int zs1 = min(mz + 1, GRES - 1);

        // Phase 1: issue ALL 8 corner gathers unconditionally (always in
        // bounds after clamp) -> 8-deep MLP, no control flow in the way.
        float a[8][3];
        #pragma unroll
        for (int k = 0; k < 8; ++k) {
            const int xi = (k & 1) ? xs1 : cx;
            const int yi = (k & 2) ? ys1 : cy;
            const int zi = (k & 4) ? zs1 : mz;
            const float* vp = voxel_in + tbase + (((size_t)xi * GRES + yi) * GRES + zi) * 3;
            a[k][0] = vp[0];
            a[k][1] = vp[1];
            a[k][2] = vp[2];
        }

        float c[8];
        c[0] = (1.f - u) * (1.f - v) * (1.f - w);
        c[1] =        u  * (1.f - v) * (1.f - w);
        c[2] = (1.f - u) *        v  * (1.f - w);
        c[3] =        u  *        v  * (1.f - w);
        c[4] = (1.f - u) * (1.f - v) *        w;
        c[5] =        u  * (1.f - v) *        w;
        c[6] = (1.f - u) *        v  *        w;
        c[7] =        u  *        v  *        w;

        const bool owner = (dxb >= 0) && (dyb >= 0);

        // Phase 2: predicated value accumulation + LDS atomic scatter.
        float vx = 0.f, vy = 0.f, vz = 0.f;
        #pragma unroll
        for (int k = 0; k < 8; ++k) {
            if (owner) {
                vx += c[k] * a[k][0];
                vy += c[k] * a[k][1];
                vz += c[k] * a[k][2];
            }
            const int xi = (k & 1) ? xs1 : cx;
            const int yi = (k & 2) ? ys1 : cy;
            const int sxi = xi - x0, syi = yi - y0;
            if (sxi >= 0 && sxi < 4 && syi >= 0 && syi < 4) {
                const int zi = (k & 4) ? zs1 : mz;
                const float lam = 1.0f / (1.0f + expf(-lrsw * c[k]));
                const int sa = ((sxi * 4 + syi) * 128 + zi) * 3;
                atomicAdd(&s_acc[sa + 0], lam * (tx - a[k][0]));
                atomicAdd(&s_acc[sa + 1], lam * (ty - a[k][1]));
                atomicAdd(&s_acc[sa + 2], lam * (tz - a[k][2]));
            }
        }
        if (owner) {
            out_value[3 * idx + 0] = vx;
            out_value[3 * idx + 1] = vy;
            out_value[3 * idx + 2] = vz;
        }
    }
    __syncthreads();

    // Coalesced write-out: out = voxel_in (L2-hot re-read) + accumulated diff.
    for (int q = tid; q < 16 * 96; q += 256) {
        int row = q / 96, r = q - row * 96;
        int ox = row >> 2, oy = row & 3;
        const size_t coff = tbase + (size_t)(x0 + ox) * 49152 + (size_t)(y0 + oy) * 384;
        float4 a = *((const float4*)(voxel_in + coff) + r);
        float4 d = s_acc4[q];
        *((float4*)(out_voxel + coff) + r) =
            make_float4(a.x + d.x, a.y + d.y, a.z + d.z, a.w + d.w);
    }
}

extern "C" void kernel_launch(void* const* d_in, const int* in_sizes, int n_in,
                              void* d_out, int out_size, void* d_ws, size_t ws_size,
                              hipStream_t stream) {
    const int*   t      = (const int*)  d_in[0];
    const float* pos    = (const float*)d_in[1];
    const float* lr     = (const float*)d_in[2];
    const float* sigma  = (const float*)d_in[3];
    const float* target = (const float*)d_in[4];
    const float* voxel  = (const float*)d_in[5];

    const int N = in_sizes[0];              // 1048576 points

    float* out_value = (float*)d_out;
    float* out_voxel = out_value + (size_t)3 * N;

    // ws: sorted(16B*N=16MB) | keys(4MB) | hist | binstart(+1) | partial | offs
    uint4*    sorted   = (uint4*)d_ws;
    unsigned* keys     = (unsigned*)(sorted + (size_t)N);
    unsigned* hist     = keys + N;
    unsigned* binstart = hist + NBINS;
    unsigned* partial  = binstart + (NBINS + 1);
    unsigned* offs     = partial + SCAN_BLOCKS;

    const int block = 256;
    const int grid  = (N + block - 1) / block;

    hipMemsetAsync(hist, 0, NBINS * sizeof(unsigned), stream);
    key_hist_kernel<<<grid, block, 0, stream>>>(t, pos, keys, hist, N);
    scanA_kernel<<<SCAN_BLOCKS, 256, 0, stream>>>(hist, binstart, partial);
    scanB_kernel<<<1, 512, 0, stream>>>(partial, offs);
    scanC_kernel<<<SCAN_BLOCKS, 256, 0, stream>>>(binstart, offs, N);
    scatter_kernel<<<grid, block, 0, stream>>>(pos, lr, sigma, target, keys,
                                               binstart, sorted, N);
    brick_kernel<<<8192, 256, 0, stream>>>(binstart, sorted, voxel,
                                           out_value, out_voxel);
}